// Round 15
// baseline (76.560 us; speedup 1.0000x reference)
//
#include <hip/hip_runtime.h>
#include <stdint.h>

#define NT 16384   // tokens = 32*512
#define SDIM 512
#define NE 8
#define BM 128
#define BN 128
#define BK 32
#define NSTEP (SDIM / BK)
#define NPAIR 28
#define MAX_TILES 156   // sum ceil(cnt/128) <= 128 + 27 = 155
#define GEMM_GRID (MAX_TILES * 4)   // 624 = 8 * 78

typedef __attribute__((ext_vector_type(8))) short short8v;
typedef __attribute__((ext_vector_type(8))) unsigned short ushort8v;
typedef __attribute__((ext_vector_type(4))) float f32x4;

#define GLOAD_LDS16(gp, lp) __builtin_amdgcn_global_load_lds( \
    (const __attribute__((address_space(1))) uint32_t*)(gp), \
    (__attribute__((address_space(3))) uint32_t*)(lp), 16, 0, 0)

__device__ __forceinline__ unsigned short f2bf(float f) {
  uint32_t x = __float_as_uint(f);
  x = (x + 0x7FFFu + ((x >> 16) & 1u)) >> 16;
  return (unsigned short)x;
}

// ---------------- fused: gating (fp64 logits, softmax, top-2, x->bf16)
//                 + expert_w fp32->bf16 + cnt zeroing ----------------
// gate arithmetic per token is IDENTICAL to the R2-verified version ->
// identical routing decisions. unroll 2 overlaps token i+1 loads with
// token i's fp64 butterfly (scheduling only, same per-token order).
__global__ __launch_bounds__(256) void gate_conv_kernel(
    const float* __restrict__ x, const float* __restrict__ gw,
    const float* __restrict__ ew,
    unsigned short* __restrict__ xb, unsigned short* __restrict__ wb,
    float* __restrict__ gates_out, float* __restrict__ wts,
    int* __restrict__ sels, int* __restrict__ cnt) {
  if (blockIdx.x == 0 && threadIdx.x < 32) cnt[threadIdx.x] = 0;

  int lane = threadIdx.x & 63;
  int wv = threadIdx.x >> 6;

  float4 ga[NE], gb[NE];
#pragma unroll
  for (int e = 0; e < NE; e++) {
    const float4* g4 = (const float4*)(gw + e * SDIM + lane * 8);
    ga[e] = g4[0]; gb[e] = g4[1];
  }

  int tbase = blockIdx.x * 16 + wv * 4;
#pragma unroll 2
  for (int i = 0; i < 4; i++) {
    int t = tbase + i;
    const float* xr = x + (size_t)t * SDIM;
    float4 xa = ((const float4*)xr)[lane * 2];
    float4 xbv = ((const float4*)xr)[lane * 2 + 1];

    ushort8v u;
    u[0] = f2bf(xa.x); u[1] = f2bf(xa.y); u[2] = f2bf(xa.z); u[3] = f2bf(xa.w);
    u[4] = f2bf(xbv.x); u[5] = f2bf(xbv.y); u[6] = f2bf(xbv.z); u[7] = f2bf(xbv.w);
    *(ushort8v*)(xb + (size_t)t * SDIM + lane * 8) = u;

    double part[NE];
#pragma unroll
    for (int e = 0; e < NE; e++) {
      double s;
      s  = (double)xa.x * ga[e].x;  s += (double)xa.y * ga[e].y;
      s += (double)xa.z * ga[e].z;  s += (double)xa.w * ga[e].w;
      s += (double)xbv.x * gb[e].x; s += (double)xbv.y * gb[e].y;
      s += (double)xbv.z * gb[e].z; s += (double)xbv.w * gb[e].w;
      part[e] = s;
    }
#pragma unroll
    for (int e = 0; e < NE; e++) {
#pragma unroll
      for (int off = 32; off >= 1; off >>= 1)
        part[e] += __shfl_xor(part[e], off, 64);
    }

    float lg[NE];
#pragma unroll
    for (int e = 0; e < NE; e++) lg[e] = (float)part[e];
    float mx = lg[0];
#pragma unroll
    for (int e = 1; e < NE; e++) mx = fmaxf(mx, lg[e]);
    float ex[NE]; float sum = 0.f;
#pragma unroll
    for (int e = 0; e < NE; e++) { ex[e] = expf(lg[e] - mx); sum += ex[e]; }
    float inv = 1.0f / sum;
    float g[NE];
#pragma unroll
    for (int e = 0; e < NE; e++) g[e] = ex[e] * inv;

    int s0 = 0; float v0 = g[0];
#pragma unroll
    for (int e = 1; e < NE; e++) if (g[e] > v0) { v0 = g[e]; s0 = e; }
    int s1 = -1; float v1 = -1.0f;
#pragma unroll
    for (int e = 0; e < NE; e++) if (e != s0 && g[e] > v1) { v1 = g[e]; s1 = e; }

    if (lane == 0) {
      float* go = gates_out + (size_t)t * NE;
#pragma unroll
      for (int e = 0; e < NE; e++) go[e] = g[e];
      wts[t * 2] = v0; wts[t * 2 + 1] = v1;
      sels[t * 2] = s0; sels[t * 2 + 1] = s1;
    }
  }

  // expert_w conversion chunk: 8 elems/thread, grid 1024*256*8 = 2.097M = NE*SDIM*SDIM
  int ci = (blockIdx.x * 256 + threadIdx.x) * 8;
  const float4* p = (const float4*)(ew + ci);
  float4 a = p[0], b = p[1];
  ushort8v w;
  w[0] = f2bf(a.x); w[1] = f2bf(a.y); w[2] = f2bf(a.z); w[3] = f2bf(a.w);
  w[4] = f2bf(b.x); w[5] = f2bf(b.y); w[6] = f2bf(b.z); w[7] = f2bf(b.w);
  *(ushort8v*)(wb + ci) = w;
}

// ---------------- block-aggregated scatter into 28 pair-buckets ----------------
__global__ __launch_bounds__(1024) void scatter_kernel(
    const int* __restrict__ sels, int* __restrict__ cnt, int* __restrict__ list) {
  __shared__ int lc[NPAIR];
  __shared__ int lb[NPAIR];
  int tid = threadIdx.x;
  if (tid < NPAIR) lc[tid] = 0;
  __syncthreads();
  int t = blockIdx.x * 1024 + tid;
  int s0 = sels[t * 2], s1 = sels[t * 2 + 1];
  int a = min(s0, s1), b = max(s0, s1);
  int tri = 7 * a - ((a * (a - 1)) >> 1) + (b - a - 1);
  int p = atomicAdd(&lc[tri], 1);
  __syncthreads();
  if (tid < NPAIR) lb[tid] = atomicAdd(cnt + tid, lc[tid]);
  __syncthreads();
  list[tri * NT + lb[tri] + p] = t;
}

// ---------------- paired grouped GEMM: R9-exact frame, on-the-fly descriptor ----
// 128x128x2slot tile, 8 waves, (512,4) no-spill, 3-stage LDS rotation,
// depth-2 prefetch, counted vmcnt(6), setprio around the MFMA cluster.
// Descriptor derived from cnt[28] per block (build_tiles dispatch removed;
// cnt is READ-ONLY during this dispatch -> no cross-XCD invalidation).
// Pair-unit swizzle: row-pair 128B units, 16B group q of pair p holds
// (row=2p+(q>>2), k16=(q&3)^(p&3)) -> source 64B-coalesced, dest linear,
// fragment reads 2-way bank alias = free.
__global__ __launch_bounds__(512, 4) void moe_gemm(
    const unsigned short* __restrict__ xb, const unsigned short* __restrict__ wbuf,
    const int* __restrict__ list, const float* __restrict__ wts,
    const int* __restrict__ sels, const int* __restrict__ cnt,
    const float* __restrict__ ebias, float* __restrict__ out) {
  // bijective XCD-chunked mapping (624 = 8*78), nb fastest within an XCD chunk.
  int flat = blockIdx.x;
  int v = (flat & 7) * (GEMM_GRID / 8) + (flat >> 3);
  int tileIdx = v >> 2, nb = v & 3;

  // on-the-fly tile descriptor from cnt[28] (uniform scalar, <=28 iters)
  int tri = -1, start = 0, rows = 0, ea = 0, eb2 = 1;
  {
    int pre = 0, a = 0, b = 1;
#pragma unroll 1
    for (int t = 0; t < NPAIR; t++) {
      int c = cnt[t];
      int nt = (c + BM - 1) / BM;
      if (tileIdx < pre + nt) {
        tri = t; start = (tileIdx - pre) * BM; rows = min(BM, c - start);
        ea = a; eb2 = b;
        break;
      }
      pre += nt;
      b++; if (b == NE) { a++; b = a + 1; }
    }
  }
  if (tri < 0 || rows == 0) return;

  int nbase = nb * BN;
  const int* gl = list + tri * NT + start;

  __shared__ unsigned short lA[3][BM * BK];        // 3 x 8KB
  __shared__ unsigned short lB[3][2 * BN * BK];    // 3 x 16KB

  int tid = threadIdx.x, lane = tid & 63, wv = tid >> 6;

  // A staging source: 1 chunk/thread. c=tid: p=c>>3, q=c&7 -> row=2p+(q>>2),
  // k16=(q&3)^(p&3).
  int pa = tid >> 3, qa = tid & 7;
  int rowA = 2 * pa + (qa >> 2);
  int k16A = (qa & 3) ^ (pa & 3);
  int tokA = (rowA < rows) ? gl[rowA] : gl[0];
  const unsigned short* srcA = xb + (size_t)tokA * SDIM + k16A * 8;

  // B staging sources: 2 chunks/thread. c=g*512+tid: slot=c>>9, then same
  // pair decode on c&511 over 128 rows.
  const unsigned short* srcB[2];
#pragma unroll
  for (int g = 0; g < 2; g++) {
    int c = g * 512 + tid;
    int slot = c >> 9;
    int cc = c & 511;
    int p = cc >> 3, q = cc & 7;
    int row = 2 * p + (q >> 2);
    int k16 = (q & 3) ^ (p & 3);
    int e = slot ? eb2 : ea;
    srcB[g] = wbuf + (size_t)(e * SDIM + nbase + row) * SDIM + k16 * 8;
  }

  char* lAb = (char*)lA;
  char* lBb = (char*)lB;
  int wm = wv >> 1, wn = wv & 1;
  int arow = wm * 32 + (lane & 15);
  int brow = wn * 64 + (lane & 15);
  int kreg = lane >> 4;

  // precomputed swizzled byte offsets for fragment reads
  int offA[2], offB[2][4];
#pragma unroll
  for (int mi = 0; mi < 2; mi++) {
    int lr = arow + mi * 16;
    int p = lr >> 1, h = lr & 1;
    offA[mi] = p * 128 + (h * 4 + (kreg ^ (p & 3))) * 16;
  }
#pragma unroll
  for (int s = 0; s < 2; s++)
#pragma unroll
    for (int ni = 0; ni < 4; ni++) {
      int lr = brow + ni * 16;
      int p = lr >> 1, h = lr & 1;
      offB[s][ni] = s * 8192 + p * 128 + (h * 4 + (kreg ^ (p & 3))) * 16;
    }

  f32x4 acc[2][2][4];
#pragma unroll
  for (int s = 0; s < 2; s++)
#pragma unroll
    for (int i = 0; i < 2; i++)
#pragma unroll
      for (int j = 0; j < 4; j++) acc[s][i][j] = (f32x4){0.f, 0.f, 0.f, 0.f};

#define STAGE(st, k0) do { \
    GLOAD_LDS16(srcA + (k0), lAb + (st) * 8192 + tid * 16); \
    _Pragma("unroll") \
    for (int g = 0; g < 2; g++) \
      GLOAD_LDS16(srcB[g] + (k0), lBb + (st) * 16384 + (g * 512 + tid) * 16); \
  } while (0)

#define COMPUTE(st) do { \
    const char* pA = lAb + (st) * 8192; \
    const char* pB = lBb + (st) * 16384; \
    short8v a[2]; \
    _Pragma("unroll") \
    for (int mi = 0; mi < 2; mi++) a[mi] = *(const short8v*)(pA + offA[mi]); \
    _Pragma("unroll") \
    for (int s = 0; s < 2; s++) { \
      short8v b[4]; \
      _Pragma("unroll") \
      for (int ni = 0; ni < 4; ni++) b[ni] = *(const short8v*)(pB + offB[s][ni]); \
      _Pragma("unroll") \
      for (int mi = 0; mi < 2; mi++) \
        _Pragma("unroll") \
        for (int ni = 0; ni < 4; ni++) \
          acc[s][mi][ni] = __builtin_amdgcn_mfma_f32_16x16x32_bf16(a[mi], b[ni], acc[s][mi][ni], 0, 0, 0); \
    } \
  } while (0)

  STAGE(0, 0);
  STAGE(1, BK);
#pragma unroll 1
  for (int t = 0; t < NSTEP; t++) {
    if (t + 2 < NSTEP) {
      STAGE((t + 2) % 3, (t + 2) * BK);               // depth-2 prefetch
      asm volatile("s_waitcnt vmcnt(6)" ::: "memory"); // stage t's 3 landed
    } else if (t + 2 == NSTEP) {
      asm volatile("s_waitcnt vmcnt(3)" ::: "memory");
    } else {
      asm volatile("s_waitcnt vmcnt(0)" ::: "memory");
    }
    __builtin_amdgcn_s_barrier();
    __builtin_amdgcn_sched_barrier(0);
    __builtin_amdgcn_s_setprio(1);
    COMPUTE(t % 3);
    __builtin_amdgcn_s_setprio(0);
    __builtin_amdgcn_s_barrier();   // all reads of stage t done before overwrite
  }

  // fused epilogue: y = relu(wA*(ya+ba) + wB*(yb+bb)), unique writer per element
  int rg = lane >> 4;
  int ncol = nbase + wn * 64 + (lane & 15);
  float bA[4], bB[4];
#pragma unroll
  for (int ni = 0; ni < 4; ni++) {
    bA[ni] = ebias[ea * SDIM + ncol + ni * 16];
    bB[ni] = ebias[eb2 * SDIM + ncol + ni * 16];
  }
#pragma unroll
  for (int mi = 0; mi < 2; mi++) {
#pragma unroll
    for (int r = 0; r < 4; r++) {
      int m = wm * 32 + mi * 16 + rg * 4 + r;
      if (m < rows) {
        int tok = gl[m];
        float2 wp = *(const float2*)&wts[tok * 2];
        int sA = sels[tok * 2];
        float wA = (sA == ea) ? wp.x : wp.y;
        float wB = (sA == ea) ? wp.y : wp.x;
        float* orow = out + (size_t)tok * SDIM + ncol;
#pragma unroll
        for (int ni = 0; ni < 4; ni++) {
          float vv = wA * (acc[0][mi][ni][r] + bA[ni]) + wB * (acc[1][mi][ni][r] + bB[ni]);
          orow[ni * 16] = fmaxf(vv, 0.f);
        }
      }
    }
  }
#undef STAGE
#undef COMPUTE
}

extern "C" void kernel_launch(void* const* d_in, const int* in_sizes, int n_in,
                              void* d_out, int out_size, void* d_ws, size_t ws_size,
                              hipStream_t stream) {
  const float* x        = (const float*)d_in[0];
  const float* gate_w   = (const float*)d_in[1];
  const float* expert_w = (const float*)d_in[2];
  const float* expert_b = (const float*)d_in[3];
  float* out = (float*)d_out;

  char* ws = (char*)d_ws;
  unsigned short* xb = (unsigned short*)(ws);                 // 16,777,216 B
  unsigned short* wb = (unsigned short*)(ws + 16777216);      //  4,194,304 B
  float* wts  = (float*)(ws + 20971520);                      //    131,072 B
  int* sels   = (int*)(ws + 21102592);                        //    131,072 B
  int* cnt    = (int*)(ws + 21233664);                        //        128 B
  int* list   = (int*)(ws + 21233792);                        //  1,835,008 B (28*NT*4)

  gate_conv_kernel<<<NT / 16, 256, 0, stream>>>(x, gate_w, expert_w, xb, wb,
                                                out + (size_t)NT * SDIM,
                                                wts, sels, cnt);
  scatter_kernel<<<NT / 1024, 1024, 0, stream>>>(sels, cnt, list);
  moe_gemm<<<GEMM_GRID, 512, 0, stream>>>(xb, wb, list, wts, sels, cnt,
                                          expert_b, out);
}

// Round 16
// 73.769 us; speedup vs baseline: 1.0378x; 1.0378x over previous
//
#include <hip/hip_runtime.h>
#include <stdint.h>

#define NT 16384   // tokens = 32*512
#define SDIM 512
#define NE 8
#define BM 128
#define BN 128
#define BK 32
#define NSTEP (SDIM / BK)
#define NPAIR 28
#define MAX_TILES 156   // sum ceil(cnt/128) <= 128 + 27 = 155
#define GEMM_GRID (MAX_TILES * 4)   // 624 = 8 * 78

typedef __attribute__((ext_vector_type(8))) short short8v;
typedef __attribute__((ext_vector_type(8))) unsigned short ushort8v;
typedef __attribute__((ext_vector_type(4))) float f32x4;

#define GLOAD_LDS16(gp, lp) __builtin_amdgcn_global_load_lds( \
    (const __attribute__((address_space(1))) uint32_t*)(gp), \
    (__attribute__((address_space(3))) uint32_t*)(lp), 16, 0, 0)

__device__ __forceinline__ unsigned short f2bf(float f) {
  uint32_t x = __float_as_uint(f);
  x = (x + 0x7FFFu + ((x >> 16) & 1u)) >> 16;
  return (unsigned short)x;
}

// ---------------- fused: gating (fp64 logits, softmax, top-2, x->bf16)
//                 + expert_w fp32->bf16 + cnt zeroing ----------------
// gate arithmetic per token is IDENTICAL to the R2-verified version ->
// identical routing decisions. convw chunk rides under gate's memory stalls.
__global__ __launch_bounds__(256) void gate_conv_kernel(
    const float* __restrict__ x, const float* __restrict__ gw,
    const float* __restrict__ ew,
    unsigned short* __restrict__ xb, unsigned short* __restrict__ wb,
    float* __restrict__ gates_out, float* __restrict__ wts,
    int* __restrict__ sels, int* __restrict__ cnt) {
  if (blockIdx.x == 0 && threadIdx.x < 32) cnt[threadIdx.x] = 0;

  int lane = threadIdx.x & 63;
  int wv = threadIdx.x >> 6;

  float4 ga[NE], gb[NE];
#pragma unroll
  for (int e = 0; e < NE; e++) {
    const float4* g4 = (const float4*)(gw + e * SDIM + lane * 8);
    ga[e] = g4[0]; gb[e] = g4[1];
  }

  int tbase = blockIdx.x * 16 + wv * 4;
#pragma unroll 1
  for (int i = 0; i < 4; i++) {
    int t = tbase + i;
    const float* xr = x + (size_t)t * SDIM;
    float4 xa = ((const float4*)xr)[lane * 2];
    float4 xbv = ((const float4*)xr)[lane * 2 + 1];

    ushort8v u;
    u[0] = f2bf(xa.x); u[1] = f2bf(xa.y); u[2] = f2bf(xa.z); u[3] = f2bf(xa.w);
    u[4] = f2bf(xbv.x); u[5] = f2bf(xbv.y); u[6] = f2bf(xbv.z); u[7] = f2bf(xbv.w);
    *(ushort8v*)(xb + (size_t)t * SDIM + lane * 8) = u;

    double part[NE];
#pragma unroll
    for (int e = 0; e < NE; e++) {
      double s;
      s  = (double)xa.x * ga[e].x;  s += (double)xa.y * ga[e].y;
      s += (double)xa.z * ga[e].z;  s += (double)xa.w * ga[e].w;
      s += (double)xbv.x * gb[e].x; s += (double)xbv.y * gb[e].y;
      s += (double)xbv.z * gb[e].z; s += (double)xbv.w * gb[e].w;
      part[e] = s;
    }
#pragma unroll
    for (int e = 0; e < NE; e++) {
#pragma unroll
      for (int off = 32; off >= 1; off >>= 1)
        part[e] += __shfl_xor(part[e], off, 64);
    }

    float lg[NE];
#pragma unroll
    for (int e = 0; e < NE; e++) lg[e] = (float)part[e];
    float mx = lg[0];
#pragma unroll
    for (int e = 1; e < NE; e++) mx = fmaxf(mx, lg[e]);
    float ex[NE]; float sum = 0.f;
#pragma unroll
    for (int e = 0; e < NE; e++) { ex[e] = expf(lg[e] - mx); sum += ex[e]; }
    float inv = 1.0f / sum;
    float g[NE];
#pragma unroll
    for (int e = 0; e < NE; e++) g[e] = ex[e] * inv;

    int s0 = 0; float v0 = g[0];
#pragma unroll
    for (int e = 1; e < NE; e++) if (g[e] > v0) { v0 = g[e]; s0 = e; }
    int s1 = -1; float v1 = -1.0f;
#pragma unroll
    for (int e = 0; e < NE; e++) if (e != s0 && g[e] > v1) { v1 = g[e]; s1 = e; }

    if (lane == 0) {
      float* go = gates_out + (size_t)t * NE;
#pragma unroll
      for (int e = 0; e < NE; e++) go[e] = g[e];
      wts[t * 2] = v0; wts[t * 2 + 1] = v1;
      sels[t * 2] = s0; sels[t * 2 + 1] = s1;
    }
  }

  // expert_w conversion chunk: 8 elems/thread, grid 1024*256*8 = 2.097M = NE*SDIM*SDIM
  int ci = (blockIdx.x * 256 + threadIdx.x) * 8;
  const float4* p = (const float4*)(ew + ci);
  float4 a = p[0], b = p[1];
  ushort8v w;
  w[0] = f2bf(a.x); w[1] = f2bf(a.y); w[2] = f2bf(a.z); w[3] = f2bf(a.w);
  w[4] = f2bf(b.x); w[5] = f2bf(b.y); w[6] = f2bf(b.z); w[7] = f2bf(b.w);
  *(ushort8v*)(wb + ci) = w;
}

// ---------------- block-aggregated scatter into 28 pair-buckets ----------------
__global__ __launch_bounds__(1024) void scatter_kernel(
    const int* __restrict__ sels, int* __restrict__ cnt, int* __restrict__ list) {
  __shared__ int lc[NPAIR];
  __shared__ int lb[NPAIR];
  int tid = threadIdx.x;
  if (tid < NPAIR) lc[tid] = 0;
  __syncthreads();
  int t = blockIdx.x * 1024 + tid;
  int s0 = sels[t * 2], s1 = sels[t * 2 + 1];
  int a = min(s0, s1), b = max(s0, s1);
  int tri = 7 * a - ((a * (a - 1)) >> 1) + (b - a - 1);
  int p = atomicAdd(&lc[tri], 1);
  __syncthreads();
  if (tid < NPAIR) lb[tid] = atomicAdd(cnt + tid, lc[tid]);
  __syncthreads();
  list[tri * NT + lb[tri] + p] = t;
}

// ---------------- tile descriptors over 28 buckets (one wave, parallel) ----------------
__global__ void build_tiles(const int* __restrict__ cnt, int4* __restrict__ desc) {
  int lane = threadIdx.x & 63;
  int c = (lane < NPAIR) ? cnt[lane] : 0;
  int nt = (c + BM - 1) / BM;
  int pre = nt;
#pragma unroll
  for (int off = 1; off < 32; off <<= 1) {
    int v = __shfl_up(pre, off, 64);
    if (lane >= off) pre += v;
  }
  pre -= nt;
  int total = __shfl(pre + nt, NPAIR - 1, 64);
  if (lane < NPAIR) {
    int a = 0, rem = lane;
    while (rem >= 7 - a) { rem -= 7 - a; a++; }
    int b = a + 1 + rem;
    int k = 0;
    for (int s = 0; s < c; s += BM, k++)
      desc[pre + k] = make_int4(a | (b << 8) | (lane << 16), s, min(BM, c - s), 0);
  }
  for (int j = total + lane; j < MAX_TILES; j += 64)
    desc[j] = make_int4(0, 0, 0, 0);
}

// ---------------- paired grouped GEMM: 128x128 tile, 8 waves, 3-stage pipeline ----
// R9-proven configuration (best measured: gemm 42.4us, total 73.8us):
// (512,4) -> no accumulator spill; 3-stage LDS rotation, depth-2 prefetch,
// counted vmcnt(6); setprio around MFMA cluster.
// LDS image: row-pair units of 128B; 16B group q of pair p holds
// (row = 2p + (q>>2), k16 = (q&3) ^ (p&3)) -> source 64B-coalesced, dest
// linear (gload_lds legal), fragment read 2-way bank alias = free.
__global__ __launch_bounds__(512, 4) void moe_gemm(
    const unsigned short* __restrict__ xb, const unsigned short* __restrict__ wbuf,
    const int* __restrict__ list, const float* __restrict__ wts,
    const int* __restrict__ sels, const int4* __restrict__ desc,
    const float* __restrict__ ebias, float* __restrict__ out) {
  // bijective XCD-chunked mapping (624 = 8*78), nb fastest within an XCD chunk.
  int flat = blockIdx.x;
  int v = (flat & 7) * (GEMM_GRID / 8) + (flat >> 3);
  int tile = v >> 2, nb = v & 3;

  int4 d = desc[tile];
  int rows = d.z;
  if (rows == 0) return;
  int ea = d.x & 255, eb2 = (d.x >> 8) & 255, tri = d.x >> 16;
  int start = d.y;
  int nbase = nb * BN;
  const int* gl = list + tri * NT + start;

  __shared__ unsigned short lA[3][BM * BK];        // 3 x 8KB
  __shared__ unsigned short lB[3][2 * BN * BK];    // 3 x 16KB

  int tid = threadIdx.x, lane = tid & 63, wv = tid >> 6;

  // A staging source: 1 chunk/thread. c=tid: p=c>>3, q=c&7 -> row=2p+(q>>2),
  // k16=(q&3)^(p&3).
  int pa = tid >> 3, qa = tid & 7;
  int rowA = 2 * pa + (qa >> 2);
  int k16A = (qa & 3) ^ (pa & 3);
  int tokA = (rowA < rows) ? gl[rowA] : gl[0];
  const unsigned short* srcA = xb + (size_t)tokA * SDIM + k16A * 8;

  // B staging sources: 2 chunks/thread. c=g*512+tid: slot=c>>9, then same
  // pair decode on c&511 over 128 rows.
  const unsigned short* srcB[2];
#pragma unroll
  for (int g = 0; g < 2; g++) {
    int c = g * 512 + tid;
    int slot = c >> 9;
    int cc = c & 511;
    int p = cc >> 3, q = cc & 7;
    int row = 2 * p + (q >> 2);
    int k16 = (q & 3) ^ (p & 3);
    int e = slot ? eb2 : ea;
    srcB[g] = wbuf + (size_t)(e * SDIM + nbase + row) * SDIM + k16 * 8;
  }

  char* lAb = (char*)lA;
  char* lBb = (char*)lB;
  int wm = wv >> 1, wn = wv & 1;
  int arow = wm * 32 + (lane & 15);
  int brow = wn * 64 + (lane & 15);
  int kreg = lane >> 4;

  // precomputed swizzled byte offsets for fragment reads
  int offA[2], offB[2][4];
#pragma unroll
  for (int mi = 0; mi < 2; mi++) {
    int lr = arow + mi * 16;
    int p = lr >> 1, h = lr & 1;
    offA[mi] = p * 128 + (h * 4 + (kreg ^ (p & 3))) * 16;
  }
#pragma unroll
  for (int s = 0; s < 2; s++)
#pragma unroll
    for (int ni = 0; ni < 4; ni++) {
      int lr = brow + ni * 16;
      int p = lr >> 1, h = lr & 1;
      offB[s][ni] = s * 8192 + p * 128 + (h * 4 + (kreg ^ (p & 3))) * 16;
    }

  f32x4 acc[2][2][4];
#pragma unroll
  for (int s = 0; s < 2; s++)
#pragma unroll
    for (int i = 0; i < 2; i++)
#pragma unroll
      for (int j = 0; j < 4; j++) acc[s][i][j] = (f32x4){0.f, 0.f, 0.f, 0.f};

#define STAGE(st, k0) do { \
    GLOAD_LDS16(srcA + (k0), lAb + (st) * 8192 + tid * 16); \
    _Pragma("unroll") \
    for (int g = 0; g < 2; g++) \
      GLOAD_LDS16(srcB[g] + (k0), lBb + (st) * 16384 + (g * 512 + tid) * 16); \
  } while (0)

#define COMPUTE(st) do { \
    const char* pA = lAb + (st) * 8192; \
    const char* pB = lBb + (st) * 16384; \
    short8v a[2]; \
    _Pragma("unroll") \
    for (int mi = 0; mi < 2; mi++) a[mi] = *(const short8v*)(pA + offA[mi]); \
    _Pragma("unroll") \
    for (int s = 0; s < 2; s++) { \
      short8v b[4]; \
      _Pragma("unroll") \
      for (int ni = 0; ni < 4; ni++) b[ni] = *(const short8v*)(pB + offB[s][ni]); \
      _Pragma("unroll") \
      for (int mi = 0; mi < 2; mi++) \
        _Pragma("unroll") \
        for (int ni = 0; ni < 4; ni++) \
          acc[s][mi][ni] = __builtin_amdgcn_mfma_f32_16x16x32_bf16(a[mi], b[ni], acc[s][mi][ni], 0, 0, 0); \
    } \
  } while (0)

  STAGE(0, 0);
  STAGE(1, BK);
#pragma unroll 1
  for (int t = 0; t < NSTEP; t++) {
    if (t + 2 < NSTEP) {
      STAGE((t + 2) % 3, (t + 2) * BK);               // depth-2 prefetch
      asm volatile("s_waitcnt vmcnt(6)" ::: "memory"); // wait only stage t's 3
    } else if (t + 2 == NSTEP) {
      asm volatile("s_waitcnt vmcnt(3)" ::: "memory");
    } else {
      asm volatile("s_waitcnt vmcnt(0)" ::: "memory");
    }
    __builtin_amdgcn_s_barrier();
    __builtin_amdgcn_sched_barrier(0);
    __builtin_amdgcn_s_setprio(1);
    COMPUTE(t % 3);
    __builtin_amdgcn_s_setprio(0);
    __builtin_amdgcn_s_barrier();   // all reads of stage t done before overwrite
  }

  // fused epilogue: y = relu(wA*(ya+ba) + wB*(yb+bb)), unique writer per element
  int rg = lane >> 4;
  int ncol = nbase + wn * 64 + (lane & 15);
  float bA[4], bB[4];
#pragma unroll
  for (int ni = 0; ni < 4; ni++) {
    bA[ni] = ebias[ea * SDIM + ncol + ni * 16];
    bB[ni] = ebias[eb2 * SDIM + ncol + ni * 16];
  }
#pragma unroll
  for (int mi = 0; mi < 2; mi++) {
#pragma unroll
    for (int r = 0; r < 4; r++) {
      int m = wm * 32 + mi * 16 + rg * 4 + r;
      if (m < rows) {
        int tok = gl[m];
        float2 wp = *(const float2*)&wts[tok * 2];
        int sA = sels[tok * 2];
        float wA = (sA == ea) ? wp.x : wp.y;
        float wB = (sA == ea) ? wp.y : wp.x;
        float* orow = out + (size_t)tok * SDIM + ncol;
#pragma unroll
        for (int ni = 0; ni < 4; ni++) {
          float vv = wA * (acc[0][mi][ni][r] + bA[ni]) + wB * (acc[1][mi][ni][r] + bB[ni]);
          orow[ni * 16] = fmaxf(vv, 0.f);
        }
      }
    }
  }
#undef STAGE
#undef COMPUTE
}

extern "C" void kernel_launch(void* const* d_in, const int* in_sizes, int n_in,
                              void* d_out, int out_size, void* d_ws, size_t ws_size,
                              hipStream_t stream) {
  const float* x        = (const float*)d_in[0];
  const float* gate_w   = (const float*)d_in[1];
  const float* expert_w = (const float*)d_in[2];
  const float* expert_b = (const float*)d_in[3];
  float* out = (float*)d_out;

  char* ws = (char*)d_ws;
  unsigned short* xb = (unsigned short*)(ws);                 // 16,777,216 B
  unsigned short* wb = (unsigned short*)(ws + 16777216);      //  4,194,304 B
  float* wts  = (float*)(ws + 20971520);                      //    131,072 B
  int* sels   = (int*)(ws + 21102592);                        //    131,072 B
  int* cnt    = (int*)(ws + 21233664);                        //        128 B
  int* list   = (int*)(ws + 21233792);                        //  1,835,008 B (28*NT*4)
  int4* desc  = (int4*)(ws + 23068800);                       //      2,496 B

  gate_conv_kernel<<<NT / 16, 256, 0, stream>>>(x, gate_w, expert_w, xb, wb,
                                                out + (size_t)NT * SDIM,
                                                wts, sels, cnt);
  scatter_kernel<<<NT / 1024, 1024, 0, stream>>>(sels, cnt, list);
  build_tiles<<<1, 64, 0, stream>>>(cnt, desc);
  moe_gemm<<<GEMM_GRID, 512, 0, stream>>>(xb, wb, list, wts, sels, desc,
                                          expert_b, out);
}